// Round 1
// baseline (113.305 us; speedup 1.0000x reference)
//
#include <hip/hip_runtime.h>

#define G 64
#define POS_THR 0.5f
#define NEG_THR 0.4f

__global__ __launch_bounds__(256) void ssd_target_kernel(
    const float* __restrict__ gt_boxes,   // (B, G, 5)
    const int*   __restrict__ gt_class,   // (B, G, 2)
    const float* __restrict__ anchors,    // (A, 4)
    float* __restrict__ out,              // [deltas B*A*4 | class B*A | tag B*A]
    int A, int B)
{
    __shared__ float s_gy1[G], s_gx1[G], s_gy2[G], s_gx2[G], s_area[G], s_cls[G];
    __shared__ int   s_valid[G];

    const int b = blockIdx.y;
    const int a = blockIdx.x * blockDim.x + threadIdx.x;

    if (threadIdx.x < G) {
        const int g = threadIdx.x;
        const float* p = gt_boxes + ((size_t)b * G + g) * 5;
        const float y1 = p[0], x1 = p[1], y2 = p[2], x2 = p[3], tag = p[4];
        s_gy1[g] = y1; s_gx1[g] = x1; s_gy2[g] = y2; s_gx2[g] = x2;
        // same op order as reference: (gx2-gx1)*(gy2-gy1)
        s_area[g] = (x2 - x1) * (y2 - y1);
        s_valid[g] = (tag != 0.0f) ? 1 : 0;
        s_cls[g]   = (float)gt_class[((size_t)b * G + g) * 2 + 0];
    }
    __syncthreads();

    if (a >= A) return;

    const float4 an = reinterpret_cast<const float4*>(anchors)[a];
    const float ay1 = an.x, ax1 = an.y, ay2 = an.z, ax2 = an.w;
    const float area_an = (ax2 - ax1) * (ay2 - ay1);

    // iou_max / argmax, replicating jnp.argmax first-occurrence tie-break
    float best = -1.0f;   // all-invalid row would give max=-1, argmax=0
    int bestg = 0;
    #pragma unroll 8
    for (int g = 0; g < G; ++g) {
        // identical op order to reference:
        // iw = max(0, min(gx2,ax2) - max(gx1,ax1))
        float iw = fmaxf(0.0f, fminf(s_gx2[g], ax2) - fmaxf(s_gx1[g], ax1));
        float ih = fmaxf(0.0f, fminf(s_gy2[g], ay2) - fmaxf(s_gy1[g], ay1));
        float inter = iw * ih;
        float denom = s_area[g] + area_an - inter;
        float iou = inter / denom;              // IEEE div — bitwise parity with np
        iou = s_valid[g] ? iou : -1.0f;
        if (iou > best) { best = iou; bestg = g; }
    }

    // matched gt box
    const float gy1 = s_gy1[bestg], gx1 = s_gx1[bestg];
    const float gy2 = s_gy2[bestg], gx2 = s_gx2[bestg];

    const float h  = ay2 - ay1;
    const float w  = ax2 - ax1;
    const float cy = (ay2 + ay1) * 0.5f;
    const float cx = (ax2 + ax1) * 0.5f;
    const float gh  = gy2 - gy1;
    const float gw  = gx2 - gx1;
    const float gcy = (gy2 + gy1) * 0.5f;
    const float gcx = (gx2 + gx1) * 0.5f;

    // deltas / BBOX_STD  (std = [0.1, 0.1, 0.2, 0.2]); threshold slack is
    // large here (5.28), so div-vs-mul rounding is irrelevant — keep ref order
    const float dy = ((gcy - cy) / h) / 0.1f;
    const float dx = ((gcx - cx) / w) / 0.1f;
    const float dh = logf(gh / h) / 0.2f;
    const float dw = logf(gw / w) / 0.2f;

    const float tag = (best >= POS_THR) ? 1.0f : ((best < NEG_THR) ? -1.0f : 0.0f);

    const size_t idx = (size_t)b * A + a;
    float4 d; d.x = dy; d.y = dx; d.z = dh; d.w = dw;
    reinterpret_cast<float4*>(out)[idx] = d;                   // deltas
    out[(size_t)B * A * 4 + idx] = s_cls[bestg];               // class_ids (as float)
    out[(size_t)B * A * 5 + idx] = tag;                        // anchors_tag
}

extern "C" void kernel_launch(void* const* d_in, const int* in_sizes, int n_in,
                              void* d_out, int out_size, void* d_ws, size_t ws_size,
                              hipStream_t stream) {
    const float* gt_boxes = (const float*)d_in[0];  // (B, G, 5) fp32
    const int*   gt_class = (const int*)d_in[1];    // (B, G, 2) int32
    const float* anchors  = (const float*)d_in[2];  // (A, 4)   fp32
    float* out = (float*)d_out;

    const int B = in_sizes[0] / (G * 5);            // 16
    const int A = in_sizes[2] / 4;                  // 65536

    dim3 grid(A / 256, B);
    dim3 block(256);
    ssd_target_kernel<<<grid, block, 0, stream>>>(gt_boxes, gt_class, anchors, out, A, B);
}

// Round 2
// 81.289 us; speedup vs baseline: 1.3938x; 1.3938x over previous
//
#include <hip/hip_runtime.h>

#define G 64
#define POS_THR 0.5f
#define NEG_THR 0.4f

__global__ __launch_bounds__(256) void ssd_target_kernel(
    const float* __restrict__ gt_boxes,   // (B, G, 5)
    const int*   __restrict__ gt_class,   // (B, G, 2)
    const float* __restrict__ anchors,    // (A, 4)
    float* __restrict__ out,              // [deltas B*A*4 | class B*A | tag B*A]
    int A, int B)
{
    // Compacted valid-gt arrays (order-preserving => argmax tie-break identical)
    __shared__ float s_gy1[G], s_gx1[G], s_gy2[G], s_gx2[G], s_area[G], s_cls[G];
    __shared__ int   s_nv;

    const int b = blockIdx.y;
    const int a = blockIdx.x * blockDim.x + threadIdx.x;

    if (threadIdx.x < G) {   // threads 0..63 == wave 0, all lanes active
        const int g = threadIdx.x;
        const float* p = gt_boxes + ((size_t)b * G + g) * 5;
        const float y1 = p[0], x1 = p[1], y2 = p[2], x2 = p[3], tag = p[4];
        const bool valid = (tag != 0.0f);
        const unsigned long long m = __ballot(valid);
        const int pos = __popcll(m & ((1ull << g) - 1ull));
        const float cls = (float)gt_class[((size_t)b * G + g) * 2 + 0];
        if (valid) {
            s_gy1[pos] = y1; s_gx1[pos] = x1; s_gy2[pos] = y2; s_gx2[pos] = x2;
            s_area[pos] = (x2 - x1) * (y2 - y1);   // ref order: (gx2-gx1)*(gy2-gy1)
            s_cls[pos]  = cls;
        }
        if (g == 0) {
            s_nv = __popcll(m);
            if (m == 0ull) {  // all invalid: ref matches gt[0] (argmax of all -1 == 0)
                s_gy1[0] = y1; s_gx1[0] = x1; s_gy2[0] = y2; s_gx2[0] = x2;
                s_cls[0] = cls;
            }
        }
    }
    __syncthreads();

    if (a >= A) return;

    const float4 an = reinterpret_cast<const float4*>(anchors)[a];
    const float ay1 = an.x, ax1 = an.y, ay2 = an.z, ax2 = an.w;
    const float area_an = (ax2 - ax1) * (ay2 - ay1);
    const int nv = s_nv;

    // iou_max / argmax over valid boxes only.
    // Valid iou >= 0 > -1 always, and invalid boxes (iou=-1) can never win,
    // so this is bit-identical to the reference's argmax over all 64.
    float best = -1.0f;
    int bestg = 0;
    #pragma unroll 4
    for (int i = 0; i < nv; ++i) {
        // identical op order to reference
        float iw = fmaxf(0.0f, fminf(s_gx2[i], ax2) - fmaxf(s_gx1[i], ax1));
        float ih = fmaxf(0.0f, fminf(s_gy2[i], ay2) - fmaxf(s_gy1[i], ay1));
        float inter = iw * ih;
        float denom = s_area[i] + area_an - inter;
        float iou = inter / denom;              // IEEE div — parity with np
        if (iou > best) { best = iou; bestg = i; }
    }

    const float gy1 = s_gy1[bestg], gx1 = s_gx1[bestg];
    const float gy2 = s_gy2[bestg], gx2 = s_gx2[bestg];

    const float h  = ay2 - ay1;
    const float w  = ax2 - ax1;
    const float cy = (ay2 + ay1) * 0.5f;
    const float cx = (ax2 + ax1) * 0.5f;
    const float gh  = gy2 - gy1;
    const float gw  = gx2 - gx1;
    const float gcy = (gy2 + gy1) * 0.5f;
    const float gcx = (gx2 + gx1) * 0.5f;

    const float dy = ((gcy - cy) / h) / 0.1f;
    const float dx = ((gcx - cx) / w) / 0.1f;
    const float dh = logf(gh / h) / 0.2f;
    const float dw = logf(gw / w) / 0.2f;

    const float tag = (best >= POS_THR) ? 1.0f : ((best < NEG_THR) ? -1.0f : 0.0f);

    const size_t idx = (size_t)b * A + a;
    float4 d; d.x = dy; d.y = dx; d.z = dh; d.w = dw;
    reinterpret_cast<float4*>(out)[idx] = d;                   // deltas
    out[(size_t)B * A * 4 + idx] = s_cls[bestg];               // class_ids (as float)
    out[(size_t)B * A * 5 + idx] = tag;                        // anchors_tag
}

extern "C" void kernel_launch(void* const* d_in, const int* in_sizes, int n_in,
                              void* d_out, int out_size, void* d_ws, size_t ws_size,
                              hipStream_t stream) {
    const float* gt_boxes = (const float*)d_in[0];  // (B, G, 5) fp32
    const int*   gt_class = (const int*)d_in[1];    // (B, G, 2) int32
    const float* anchors  = (const float*)d_in[2];  // (A, 4)   fp32
    float* out = (float*)d_out;

    const int B = in_sizes[0] / (G * 5);            // 16
    const int A = in_sizes[2] / 4;                  // 65536

    dim3 grid(A / 256, B);
    dim3 block(256);
    ssd_target_kernel<<<grid, block, 0, stream>>>(gt_boxes, gt_class, anchors, out, A, B);
}

// Round 3
// 79.445 us; speedup vs baseline: 1.4262x; 1.0232x over previous
//
#include <hip/hip_runtime.h>

#define G 64
#define POS_THR 0.5f
#define NEG_THR 0.4f

__global__ __launch_bounds__(256) void ssd_target_kernel(
    const float* __restrict__ gt_boxes,   // (B, G, 5)
    const int*   __restrict__ gt_class,   // (B, G, 2)
    const float* __restrict__ anchors,    // (A, 4)
    float* __restrict__ out,              // [deltas B*A*4 | class B*A | tag B*A]
    int A, int B)
{
    // Compacted valid-gt arrays (order-preserving => argmax tie-break identical)
    __shared__ float4 s_box[G];            // (y1, x1, y2, x2)
    __shared__ float  s_area[G], s_cls[G];
    __shared__ int    s_nv;

    const int b = blockIdx.y;
    const int a = blockIdx.x * blockDim.x + threadIdx.x;

    if (threadIdx.x < G) {   // threads 0..63 == wave 0, all lanes active
        const int g = threadIdx.x;
        const float* p = gt_boxes + ((size_t)b * G + g) * 5;
        const float y1 = p[0], x1 = p[1], y2 = p[2], x2 = p[3], tag = p[4];
        const bool valid = (tag != 0.0f);
        const unsigned long long m = __ballot(valid);
        const int pos = __popcll(m & ((1ull << g) - 1ull));
        const float cls = (float)gt_class[((size_t)b * G + g) * 2 + 0];
        if (valid) {
            s_box[pos] = make_float4(y1, x1, y2, x2);
            s_area[pos] = (x2 - x1) * (y2 - y1);   // ref order: (gx2-gx1)*(gy2-gy1)
            s_cls[pos]  = cls;
        }
        if (g == 0) {
            s_nv = __popcll(m);
            if (m == 0ull) {  // all invalid: ref matches gt[0] (argmax of all -1 == 0)
                s_box[0] = make_float4(y1, x1, y2, x2);
                s_cls[0] = cls;
            }
        }
    }
    __syncthreads();

    if (a >= A) return;

    const float4 an = reinterpret_cast<const float4*>(anchors)[a];
    const float ay1 = an.x, ax1 = an.y, ay2 = an.z, ax2 = an.w;
    const float area_an = (ax2 - ax1) * (ay2 - ay1);
    const int nv = s_nv;

    // ---- Pass 1: approx IoU via v_rcp (no IEEE div, no denorm-mode toggles).
    // approx = exact_iou * (1+e), |e| <~ 2^-22.  Track top-2 + first-occurrence
    // argmax; a top-2 relative gap > 1e-5 (40x error bound) proves the approx
    // argmax equals the exact-rounded argmax.
    float best_a = -1.0f, second_a = -1.0f;
    int bestg = 0;
    #pragma unroll 4
    for (int i = 0; i < nv; ++i) {
        const float4 gb = s_box[i];
        float iw = fmaxf(0.0f, fminf(gb.w, ax2) - fmaxf(gb.y, ax1));
        float ih = fmaxf(0.0f, fminf(gb.z, ay2) - fmaxf(gb.x, ay1));
        float inter = iw * ih;
        float denom = s_area[i] + area_an - inter;
        float apx = inter * __builtin_amdgcn_rcpf(denom);
        bestg = (apx > best_a) ? i : bestg;            // strict > : first occurrence
        second_a = fmaxf(second_a, fminf(apx, best_a));
        best_a = fmaxf(best_a, apx);
    }

    // best_a == 0  =>  every inter == 0  =>  approx AND exact IoU are all
    // exactly 0; ordering identical, winner = first valid box. No fallback.
    const bool need_exact = (best_a > 0.0f) && (second_a >= best_a * (1.0f - 1e-5f));

    float q;          // exact-rounded iou_max (reference parity)
    int win = bestg;
    if (nv == 0) {
        q = -1.0f;    // reference: all ious -1, argmax = 0
        win = 0;
    } else if (need_exact) {
        // Rare near-tie: replicate reference bit-for-bit (IEEE div, strict >).
        float be = -1.0f; int bi = 0;
        for (int i = 0; i < nv; ++i) {
            const float4 gb = s_box[i];
            float iw = fmaxf(0.0f, fminf(gb.w, ax2) - fmaxf(gb.y, ax1));
            float ih = fmaxf(0.0f, fminf(gb.z, ay2) - fmaxf(gb.x, ay1));
            float inter = iw * ih;
            float denom = s_area[i] + area_an - inter;
            float iou = inter / denom;                 // IEEE div
            if (iou > be) { be = iou; bi = i; }
        }
        q = be; win = bi;
    } else {
        // Unique winner: one exact IEEE div for the tag thresholds.
        const float4 gb = s_box[win];
        float iw = fmaxf(0.0f, fminf(gb.w, ax2) - fmaxf(gb.y, ax1));
        float ih = fmaxf(0.0f, fminf(gb.z, ay2) - fmaxf(gb.x, ay1));
        float inter = iw * ih;
        float denom = s_area[win] + area_an - inter;
        q = inter / denom;                             // IEEE div
    }

    const float4 gw_box = s_box[win];
    const float gy1 = gw_box.x, gx1 = gw_box.y, gy2 = gw_box.z, gx2 = gw_box.w;

    const float h  = ay2 - ay1;
    const float w  = ax2 - ax1;
    const float cy = (ay2 + ay1) * 0.5f;
    const float cx = (ax2 + ax1) * 0.5f;
    const float gh  = gy2 - gy1;
    const float gw  = gx2 - gx1;
    const float gcy = (gy2 + gy1) * 0.5f;
    const float gcx = (gx2 + gx1) * 0.5f;

    const float dy = ((gcy - cy) / h) / 0.1f;
    const float dx = ((gcx - cx) / w) / 0.1f;
    const float dh = logf(gh / h) / 0.2f;
    const float dw = logf(gw / w) / 0.2f;

    const float tag = (q >= POS_THR) ? 1.0f : ((q < NEG_THR) ? -1.0f : 0.0f);

    const size_t idx = (size_t)b * A + a;
    float4 d; d.x = dy; d.y = dx; d.z = dh; d.w = dw;
    reinterpret_cast<float4*>(out)[idx] = d;                   // deltas
    out[(size_t)B * A * 4 + idx] = s_cls[win];                 // class_ids (as float)
    out[(size_t)B * A * 5 + idx] = tag;                        // anchors_tag
}

extern "C" void kernel_launch(void* const* d_in, const int* in_sizes, int n_in,
                              void* d_out, int out_size, void* d_ws, size_t ws_size,
                              hipStream_t stream) {
    const float* gt_boxes = (const float*)d_in[0];  // (B, G, 5) fp32
    const int*   gt_class = (const int*)d_in[1];    // (B, G, 2) int32
    const float* anchors  = (const float*)d_in[2];  // (A, 4)   fp32
    float* out = (float*)d_out;

    const int B = in_sizes[0] / (G * 5);            // 16
    const int A = in_sizes[2] / 4;                  // 65536

    dim3 grid(A / 256, B);
    dim3 block(256);
    ssd_target_kernel<<<grid, block, 0, stream>>>(gt_boxes, gt_class, anchors, out, A, B);
}

// Round 4
// 78.683 us; speedup vs baseline: 1.4400x; 1.0097x over previous
//
#include <hip/hip_runtime.h>

#define G 64
#define K 4            // anchors per thread
#define POS_THR 0.5f
#define NEG_THR 0.4f

__global__ __launch_bounds__(256) void ssd_target_kernel(
    const float* __restrict__ gt_boxes,   // (B, G, 5)
    const int*   __restrict__ gt_class,   // (B, G, 2)
    const float* __restrict__ anchors,    // (A, 4)
    float* __restrict__ out,              // [deltas B*A*4 | class B*A | tag B*A]
    int A, int B)
{
    // Compacted valid-gt arrays (order-preserving => argmax tie-break identical)
    __shared__ float4 s_box[G];            // (y1, x1, y2, x2)
    __shared__ float  s_area[G], s_cls[G];
    __shared__ int    s_nv;

    const int b = blockIdx.y;

    if (threadIdx.x < G) {   // threads 0..63 == wave 0, all lanes active
        const int g = threadIdx.x;
        const float* p = gt_boxes + ((size_t)b * G + g) * 5;
        const float y1 = p[0], x1 = p[1], y2 = p[2], x2 = p[3], tagv = p[4];
        const bool valid = (tagv != 0.0f);
        const unsigned long long m = __ballot(valid);
        const int pos = __popcll(m & ((1ull << g) - 1ull));
        const float cls = (float)gt_class[((size_t)b * G + g) * 2 + 0];
        if (valid) {
            s_box[pos] = make_float4(y1, x1, y2, x2);
            s_area[pos] = (x2 - x1) * (y2 - y1);   // ref order: (gx2-gx1)*(gy2-gy1)
            s_cls[pos]  = cls;
        }
        if (g == 0) {
            s_nv = __popcll(m);
            if (m == 0ull) {  // all invalid: ref matches gt[0] (argmax of all -1 == 0)
                s_box[0] = make_float4(y1, x1, y2, x2);
                s_cls[0] = cls;
            }
        }
    }
    __syncthreads();

    const int t  = threadIdx.x;
    const int a0 = blockIdx.x * (256 * K) + t;     // stride-256 anchors => coalesced

    float4 an[K];
    float  area_an[K];
    #pragma unroll
    for (int k = 0; k < K; ++k) {
        an[k] = reinterpret_cast<const float4*>(anchors)[a0 + k * 256];
        area_an[k] = (an[k].w - an[k].y) * (an[k].z - an[k].x);
    }

    const int nv = s_nv;
    float best[K], second[K];
    int   bg[K];
    #pragma unroll
    for (int k = 0; k < K; ++k) { best[k] = -1.0f; second[k] = -1.0f; bg[k] = 0; }

    // ---- Pass 1: approx IoU via v_rcp; one LDS b128+b32 feeds 4 anchors.
    // Top-2 + first-occurrence argmax; top-2 relative gap > 1e-5 (40x the
    // ~2^-22 rcp error bound) proves approx argmax == exact-rounded argmax.
    #pragma unroll 2
    for (int i = 0; i < nv; ++i) {
        const float4 gb = s_box[i];
        const float  ga = s_area[i];
        #pragma unroll
        for (int k = 0; k < K; ++k) {
            float iw = fmaxf(0.0f, fminf(gb.w, an[k].w) - fmaxf(gb.y, an[k].y));
            float ih = fmaxf(0.0f, fminf(gb.z, an[k].z) - fmaxf(gb.x, an[k].x));
            float inter = iw * ih;
            float denom = ga + area_an[k] - inter;
            float apx = inter * __builtin_amdgcn_rcpf(denom);
            bg[k]     = (apx > best[k]) ? i : bg[k];         // strict > : first occurrence
            second[k] = fmaxf(second[k], fminf(apx, best[k]));
            best[k]   = fmaxf(best[k], apx);
        }
    }

    #pragma unroll
    for (int k = 0; k < K; ++k) {
        const float ay1 = an[k].x, ax1 = an[k].y, ay2 = an[k].z, ax2 = an[k].w;
        int   win = bg[k];
        float q;                    // exact-rounded iou_max (reference parity)
        if (nv == 0) {
            q = -1.0f; win = 0;     // ref: all ious -1, argmax = 0
        } else {
            // best==0 => every inter==0 exactly in both approx and exact;
            // winner = first valid box, no fallback needed.
            const bool need_exact =
                (best[k] > 0.0f) && (second[k] >= best[k] * (1.0f - 1e-5f));
            if (need_exact) {
                // Rare near-tie: replicate reference bit-for-bit (IEEE div).
                float be = -1.0f; int bi = 0;
                for (int i = 0; i < nv; ++i) {
                    const float4 gb = s_box[i];
                    float iw = fmaxf(0.0f, fminf(gb.w, ax2) - fmaxf(gb.y, ax1));
                    float ih = fmaxf(0.0f, fminf(gb.z, ay2) - fmaxf(gb.x, ay1));
                    float inter = iw * ih;
                    float denom = s_area[i] + area_an[k] - inter;
                    float iou = inter / denom;               // IEEE div
                    if (iou > be) { be = iou; bi = i; }
                }
                q = be; win = bi;
            } else {
                // Unique winner: one exact IEEE div for the tag thresholds.
                const float4 gb = s_box[win];
                float iw = fmaxf(0.0f, fminf(gb.w, ax2) - fmaxf(gb.y, ax1));
                float ih = fmaxf(0.0f, fminf(gb.z, ay2) - fmaxf(gb.x, ay1));
                float inter = iw * ih;
                float denom = s_area[win] + area_an[k] - inter;
                q = inter / denom;                           // IEEE div
            }
        }

        const float4 gb = s_box[win];
        const float h  = ay2 - ay1;
        const float w  = ax2 - ax1;
        const float rh = __builtin_amdgcn_rcpf(h);
        const float rw = __builtin_amdgcn_rcpf(w);
        const float cy = (ay2 + ay1) * 0.5f;
        const float cx = (ax2 + ax1) * 0.5f;
        const float gh  = gb.z - gb.x;
        const float gw  = gb.w - gb.y;
        const float gcy = (gb.z + gb.x) * 0.5f;
        const float gcx = (gb.w + gb.y) * 0.5f;

        // deltas have ~5.28 absmax slack: rcp/log2 approx (err ~1e-6) is safe.
        const float dy = (gcy - cy) * rh * 10.0f;
        const float dx = (gcx - cx) * rw * 10.0f;
        const float dh = __log2f(gh * rh) * 3.4657359028f;   // ln(x)*5
        const float dw = __log2f(gw * rw) * 3.4657359028f;

        const float tag = (q >= POS_THR) ? 1.0f : ((q < NEG_THR) ? -1.0f : 0.0f);

        const size_t idx = (size_t)b * A + (size_t)(a0 + k * 256);
        float4 d; d.x = dy; d.y = dx; d.z = dh; d.w = dw;
        reinterpret_cast<float4*>(out)[idx] = d;             // deltas
        out[(size_t)B * A * 4 + idx] = s_cls[win];           // class_ids (as float)
        out[(size_t)B * A * 5 + idx] = tag;                  // anchors_tag
    }
}

extern "C" void kernel_launch(void* const* d_in, const int* in_sizes, int n_in,
                              void* d_out, int out_size, void* d_ws, size_t ws_size,
                              hipStream_t stream) {
    const float* gt_boxes = (const float*)d_in[0];  // (B, G, 5) fp32
    const int*   gt_class = (const int*)d_in[1];    // (B, G, 2) int32
    const float* anchors  = (const float*)d_in[2];  // (A, 4)   fp32
    float* out = (float*)d_out;

    const int B = in_sizes[0] / (G * 5);            // 16
    const int A = in_sizes[2] / 4;                  // 65536

    dim3 grid(A / (256 * K), B);
    dim3 block(256);
    ssd_target_kernel<<<grid, block, 0, stream>>>(gt_boxes, gt_class, anchors, out, A, B);
}

// Round 5
// 77.604 us; speedup vs baseline: 1.4600x; 1.0139x over previous
//
#include <hip/hip_runtime.h>

#define G 64
#define K 2            // anchors per thread
#define POS_THR 0.5f
#define NEG_THR 0.4f

__global__ __launch_bounds__(256) void ssd_target_kernel(
    const float* __restrict__ gt_boxes,   // (B, G, 5)
    const int*   __restrict__ gt_class,   // (B, G, 2)
    const float* __restrict__ anchors,    // (A, 4)
    float* __restrict__ out,              // [deltas B*A*4 | class B*A | tag B*A]
    int A, int B)
{
    // Compacted valid-gt arrays (order-preserving => argmax tie-break identical)
    __shared__ float4 s_box[G];            // (y1, x1, y2, x2)
    __shared__ float  s_area[G], s_cls[G];
    __shared__ int    s_nv;

    const int b = blockIdx.y;

    if (threadIdx.x < G) {   // threads 0..63 == wave 0, all lanes active
        const int g = threadIdx.x;
        const float* p = gt_boxes + ((size_t)b * G + g) * 5;
        const float y1 = p[0], x1 = p[1], y2 = p[2], x2 = p[3], tagv = p[4];
        const bool valid = (tagv != 0.0f);
        const unsigned long long m = __ballot(valid);
        const int pos = __popcll(m & ((1ull << g) - 1ull));
        const float cls = (float)gt_class[((size_t)b * G + g) * 2 + 0];
        if (valid) {
            s_box[pos] = make_float4(y1, x1, y2, x2);
            s_area[pos] = (x2 - x1) * (y2 - y1);   // ref order: (gx2-gx1)*(gy2-gy1)
            s_cls[pos]  = cls;
        }
        if (g == 0) {
            s_nv = __popcll(m);
            if (m == 0ull) {  // all invalid: ref matches gt[0] (argmax of all -1 == 0)
                s_box[0] = make_float4(y1, x1, y2, x2);
                s_cls[0] = cls;
            }
        }
    }
    __syncthreads();

    const int t  = threadIdx.x;
    const int a0 = blockIdx.x * (256 * K) + t;     // stride-256 anchors => coalesced

    float4 an[K];
    float  area_an[K];
    #pragma unroll
    for (int k = 0; k < K; ++k) {
        an[k] = reinterpret_cast<const float4*>(anchors)[a0 + k * 256];
        area_an[k] = (an[k].w - an[k].y) * (an[k].z - an[k].x);
    }

    const int nv = s_nv;
    float best[K], second[K];
    int   bg[K];
    #pragma unroll
    for (int k = 0; k < K; ++k) { best[k] = -1.0f; second[k] = -1.0f; bg[k] = 0; }

    // ---- Pass 1: approx IoU via v_rcp; one LDS b128+b32 feeds K anchors.
    // Top-2 + first-occurrence argmax; top-2 relative gap > 1e-5 (40x the
    // ~2^-22 rcp error bound) proves approx argmax == exact-rounded argmax.
    #pragma unroll 4
    for (int i = 0; i < nv; ++i) {
        const float4 gb = s_box[i];
        const float  ga = s_area[i];
        #pragma unroll
        for (int k = 0; k < K; ++k) {
            float iw = fmaxf(0.0f, fminf(gb.w, an[k].w) - fmaxf(gb.y, an[k].y));
            float ih = fmaxf(0.0f, fminf(gb.z, an[k].z) - fmaxf(gb.x, an[k].x));
            float inter = iw * ih;
            float denom = ga + area_an[k] - inter;
            float apx = inter * __builtin_amdgcn_rcpf(denom);
            bg[k]     = (apx > best[k]) ? i : bg[k];         // strict > : first occurrence
            // runner-up update: median(second, apx, best) == max(second, min(apx, best))
            second[k] = __builtin_amdgcn_fmed3f(second[k], apx, best[k]);
            best[k]   = fmaxf(best[k], apx);
        }
    }

    #pragma unroll
    for (int k = 0; k < K; ++k) {
        const float ay1 = an[k].x, ax1 = an[k].y, ay2 = an[k].z, ax2 = an[k].w;
        int   win = bg[k];
        float q;                    // exact-rounded iou_max (reference parity)
        if (nv == 0) {
            q = -1.0f; win = 0;     // ref: all ious -1, argmax = 0
        } else {
            // best==0 => every inter==0 exactly in both approx and exact;
            // winner = first valid box, no fallback needed.
            const bool need_exact =
                (best[k] > 0.0f) && (second[k] >= best[k] * (1.0f - 1e-5f));
            if (need_exact) {
                // Rare near-tie: replicate reference bit-for-bit (IEEE div).
                float be = -1.0f; int bi = 0;
                for (int i = 0; i < nv; ++i) {
                    const float4 gb = s_box[i];
                    float iw = fmaxf(0.0f, fminf(gb.w, ax2) - fmaxf(gb.y, ax1));
                    float ih = fmaxf(0.0f, fminf(gb.z, ay2) - fmaxf(gb.x, ay1));
                    float inter = iw * ih;
                    float denom = s_area[i] + area_an[k] - inter;
                    float iou = inter / denom;               // IEEE div
                    if (iou > be) { be = iou; bi = i; }
                }
                q = be; win = bi;
            } else {
                // Unique winner: one exact IEEE div for the tag thresholds.
                const float4 gb = s_box[win];
                float iw = fmaxf(0.0f, fminf(gb.w, ax2) - fmaxf(gb.y, ax1));
                float ih = fmaxf(0.0f, fminf(gb.z, ay2) - fmaxf(gb.x, ay1));
                float inter = iw * ih;
                float denom = s_area[win] + area_an[k] - inter;
                q = inter / denom;                           // IEEE div
            }
        }

        const float4 gb = s_box[win];
        const float h  = ay2 - ay1;
        const float w  = ax2 - ax1;
        const float rh = __builtin_amdgcn_rcpf(h);
        const float rw = __builtin_amdgcn_rcpf(w);
        const float cy = (ay2 + ay1) * 0.5f;
        const float cx = (ax2 + ax1) * 0.5f;
        const float gh  = gb.z - gb.x;
        const float gw  = gb.w - gb.y;
        const float gcy = (gb.z + gb.x) * 0.5f;
        const float gcx = (gb.w + gb.y) * 0.5f;

        // deltas have ~5.28 absmax slack: rcp/log2 approx (err ~1e-6) is safe.
        const float dy = (gcy - cy) * rh * 10.0f;
        const float dx = (gcx - cx) * rw * 10.0f;
        const float dh = __log2f(gh * rh) * 3.4657359028f;   // ln(x)*5
        const float dw = __log2f(gw * rw) * 3.4657359028f;

        const float tag = (q >= POS_THR) ? 1.0f : ((q < NEG_THR) ? -1.0f : 0.0f);

        const size_t idx = (size_t)b * A + (size_t)(a0 + k * 256);
        float4 d; d.x = dy; d.y = dx; d.z = dh; d.w = dw;
        reinterpret_cast<float4*>(out)[idx] = d;             // deltas
        out[(size_t)B * A * 4 + idx] = s_cls[win];           // class_ids (as float)
        out[(size_t)B * A * 5 + idx] = tag;                  // anchors_tag
    }
}

extern "C" void kernel_launch(void* const* d_in, const int* in_sizes, int n_in,
                              void* d_out, int out_size, void* d_ws, size_t ws_size,
                              hipStream_t stream) {
    const float* gt_boxes = (const float*)d_in[0];  // (B, G, 5) fp32
    const int*   gt_class = (const int*)d_in[1];    // (B, G, 2) int32
    const float* anchors  = (const float*)d_in[2];  // (A, 4)   fp32
    float* out = (float*)d_out;

    const int B = in_sizes[0] / (G * 5);            // 16
    const int A = in_sizes[2] / 4;                  // 65536

    dim3 grid(A / (256 * K), B);
    dim3 block(256);
    ssd_target_kernel<<<grid, block, 0, stream>>>(gt_boxes, gt_class, anchors, out, A, B);
}